// Round 6
// baseline (110.219 us; speedup 1.0000x reference)
//
#include <hip/hip_runtime.h>
#include <hip/hip_bf16.h>

#define S_LEN 2048
#define BH_TOTAL 64
#define D_DIM 64
#define NT 32          // S_LEN / 64 kv tiles

typedef float f32x4 __attribute__((ext_vector_type(4)));
typedef float f32x16 __attribute__((ext_vector_type(16)));
typedef __bf16 bf16x8 __attribute__((ext_vector_type(8)));
typedef unsigned short u16x8 __attribute__((ext_vector_type(8)));
typedef unsigned int u32;
typedef u32 u32x2 __attribute__((ext_vector_type(2)));
typedef u32 u32x4 __attribute__((ext_vector_type(4)));

union BF8 { u32x4 w; u16x8 u; bf16x8 b; };

#if __has_builtin(__builtin_amdgcn_exp2f)
#define EX2(x) __builtin_amdgcn_exp2f(x)
#else
#define EX2(x) exp2f(x)
#endif

__device__ __forceinline__ unsigned short f2b(float f) {
  __bf16 h = (__bf16)f;
  return __builtin_bit_cast(unsigned short, h);
}
__device__ __forceinline__ u32 pk2(float a, float b) {
  return (u32)f2b(a) | ((u32)f2b(b) << 16);
}

__device__ __forceinline__ u32x2 pl32(u32 x, u32 y) {
#if __has_builtin(__builtin_amdgcn_permlane32_swap)
  return __builtin_amdgcn_permlane32_swap(x, y, false, false);
#else
  u32 xs = (u32)__shfl_xor((int)x, 32);
  u32 ys = (u32)__shfl_xor((int)y, 32);
  int hi = (int)(threadIdx.x & 32);
  u32x2 r;
  r.x = hi ? ys : x;
  r.y = hi ? y : xs;
  return r;
#endif
}

__device__ __forceinline__ void gload16(const unsigned short* g, unsigned short* l) {
  __builtin_amdgcn_global_load_lds(
      (const __attribute__((address_space(1))) unsigned int*)g,
      (__attribute__((address_space(3))) unsigned int*)l, 16, 0, 0);
}

// ---------------- pre-pass 1: K fp32 -> bf16 (flat) ----------------
__global__ __launch_bounds__(256)
void cvt_k(const float* __restrict__ K, unsigned short* __restrict__ Kb) {
  int i = blockIdx.x * 256 + threadIdx.x;
  const f32x4* src = (const f32x4*)K;
  f32x4 a = src[2 * i], b = src[2 * i + 1];
  u16x8 o;
  #pragma unroll
  for (int j = 0; j < 4; ++j) { o[j] = f2b(a[j]); o[j + 4] = f2b(b[j]); }
  ((u16x8*)Kb)[i] = o;
}

// ---------------- pre-pass 2: V fp32 [bh][s][d] -> bf16 Vt [bh][d][s] ----------------
__global__ __launch_bounds__(256)
void tr_v(const float* __restrict__ V, unsigned short* __restrict__ Vt) {
  __shared__ unsigned short T[64][72];
  int bh = blockIdx.x >> 5, t5 = blockIdx.x & 31;
  int s0 = t5 * 64;
  int tid = threadIdx.x;
  {
    int s = tid >> 2, d0 = (tid & 3) * 16;
    const float* src = V + ((size_t)bh * S_LEN + s0 + s) * D_DIM + d0;
    #pragma unroll
    for (int j = 0; j < 16; j += 4) {
      f32x4 x = *(const f32x4*)(src + j);
      #pragma unroll
      for (int q2 = 0; q2 < 4; ++q2) T[d0 + j + q2][s] = f2b(x[q2]);
    }
  }
  __syncthreads();
  {
    int d = tid >> 2, c0 = (tid & 3) * 16;
    unsigned short* dst = Vt + ((size_t)bh * D_DIM + d) * S_LEN + s0 + c0;
    u16x8 o;
    #pragma unroll
    for (int q2 = 0; q2 < 8; ++q2) o[q2] = T[d][c0 + q2];
    *(u16x8*)dst = o;
    #pragma unroll
    for (int q2 = 0; q2 < 8; ++q2) o[q2] = T[d][c0 + 8 + q2];
    *(u16x8*)(dst + 8) = o;
  }
}

// ---- exp2 + pack + permlane: s-tile (f32x16) -> two P B-frags ----
__device__ __forceinline__ void exppack(const f32x16 sv, float& ls, BF8& pA, BF8& pB) {
  u32 wlo[4], whi[4];
  #pragma unroll
  for (int b2 = 0; b2 < 4; ++b2) {
    float e0 = EX2(sv[4 * b2 + 0]), e1 = EX2(sv[4 * b2 + 1]);
    float e2 = EX2(sv[4 * b2 + 2]), e3 = EX2(sv[4 * b2 + 3]);
    ls += (e0 + e1) + (e2 + e3);
    wlo[b2] = pk2(e0, e1);
    whi[b2] = pk2(e2, e3);
  }
  u32x2 rlo = pl32(wlo[0], wlo[1]);
  u32x2 rhi = pl32(whi[0], whi[1]);
  pA.w[0] = rlo.x; pA.w[1] = rhi.x; pA.w[2] = rlo.y; pA.w[3] = rhi.y;
  rlo = pl32(wlo[2], wlo[3]);
  rhi = pl32(whi[2], whi[3]);
  pB.w[0] = rlo.x; pB.w[1] = rhi.x; pB.w[2] = rlo.y; pB.w[3] = rhi.y;
}

// ---- QK cluster with 1-step LDS read-ahead ----
__device__ __forceinline__ void qk_cluster(const char* kR, int rb, const int* cx,
                                           const BF8* qf, f32x16& s0, f32x16& s1) {
  BF8 ka, kb, kan, kbn;
  ka.u = *(const u16x8*)(kR + rb + cx[0]);
  kb.u = *(const u16x8*)(kR + 4096 + rb + cx[0]);
  __builtin_amdgcn_s_setprio(1);
  #pragma unroll
  for (int f = 0; f < 4; ++f) {
    if (f < 3) {
      kan.u = *(const u16x8*)(kR + rb + cx[f + 1]);
      kbn.u = *(const u16x8*)(kR + 4096 + rb + cx[f + 1]);
    }
    s0 = __builtin_amdgcn_mfma_f32_32x32x16_bf16(ka.b, qf[f].b, s0, 0, 0, 0);
    s1 = __builtin_amdgcn_mfma_f32_32x32x16_bf16(kb.b, qf[f].b, s1, 0, 0, 0);
    if (f < 3) { ka = kan; kb = kbn; }
  }
  __builtin_amdgcn_s_setprio(0);
}

// ---- PV cluster with 1-step LDS read-ahead ----
__device__ __forceinline__ void pv_cluster(const char* vA, int rb, const int* cx,
                                           const BF8& p0, const BF8& p1,
                                           const BF8& p2, const BF8& p3,
                                           f32x16& oa0, f32x16& oa1) {
  const BF8* pf[4] = {&p0, &p1, &p2, &p3};
  BF8 va, vb, van, vbn;
  va.u = *(const u16x8*)(vA + rb + cx[0]);
  vb.u = *(const u16x8*)(vA + 4096 + rb + cx[0]);
  __builtin_amdgcn_s_setprio(1);
  #pragma unroll
  for (int j = 0; j < 4; ++j) {
    if (j < 3) {
      van.u = *(const u16x8*)(vA + rb + cx[j + 1]);
      vbn.u = *(const u16x8*)(vA + 4096 + rb + cx[j + 1]);
    }
    oa0 = __builtin_amdgcn_mfma_f32_32x32x16_bf16(va.b, pf[j]->b, oa0, 0, 0, 0);
    oa1 = __builtin_amdgcn_mfma_f32_32x32x16_bf16(vb.b, pf[j]->b, oa1, 0, 0, 0);
    if (j < 3) { va = van; vb = vbn; }
  }
  __builtin_amdgcn_s_setprio(0);
}

// ---------------- main attention: T15 pipeline, PV(t) overlapped with QK(t+1) ----------------
// LDS phys layout: phys_byte(row, colbyte) = row*128 + (colbyte ^ ((row&7)<<4))
__global__ __launch_bounds__(256, 4)
void attn_fwd(const float* __restrict__ Q, const unsigned short* __restrict__ Kb,
              const unsigned short* __restrict__ Vt, float* __restrict__ O) {
  const int wg = blockIdx.x;
  const int id = (wg & 7) * 128 + (wg >> 3);   // bijective XCD swizzle (1024 % 8 == 0)
  const int qt = id & 15;
  const int bh = id >> 4;

  const int tid = threadIdx.x;
  const int w = tid >> 6;
  const int ln = tid & 63;
  const int l31 = ln & 31;
  const int h = ln >> 5;

  __shared__ __align__(16) unsigned short Ks[2][4096];   // K [kv][d], swizzled, dbuf
  __shared__ __align__(16) unsigned short Vs[3][4096];   // V^T [d][kv], swizzled, 3-buf

  const size_t hbase = (size_t)bh * S_LEN * D_DIM;
  const unsigned short* Kh = Kb + hbase;
  const unsigned short* Vh = Vt + hbase;

  const int q0 = qt * 128 + w * 32;

  // ---- Q B-fragments, scale*log2e folded ----
  BF8 qf[4];
  {
    const float sc = 0.125f * 1.44269504088896f;
    const float* qp = Q + hbase + (size_t)(q0 + l31) * D_DIM + h * 8;
    #pragma unroll
    for (int f = 0; f < 4; ++f) {
      f32x4 a = *(const f32x4*)(qp + f * 16);
      f32x4 b = *(const f32x4*)(qp + f * 16 + 4);
      #pragma unroll
      for (int j = 0; j < 4; ++j) {
        qf[f].u[j]     = f2b(a[j] * sc);
        qf[f].u[j + 4] = f2b(b[j] * sc);
      }
    }
  }

  // ---- staging sources (inverse-swizzled), wave w covers rows [w*16, w*16+16) ----
  const int srow = ln >> 3;
  const int scol = ((ln & 7) ^ srow) * 8;
  const unsigned short* ks0 = Kh + (size_t)(w * 16 + srow) * D_DIM + scol;
  const unsigned short* vs0 = Vh + (size_t)(w * 16 + srow) * S_LEN + scol;

  // ---- fragment read offsets ----
  const int swz = (ln & 7) << 4;
  const int rb = l31 * 128;
  int cx[4];
  #pragma unroll
  for (int m = 0; m < 4; ++m) cx[m] = (m * 32 + h * 16) ^ swz;

  f32x16 oa0, oa1;
  #pragma unroll
  for (int j = 0; j < 16; ++j) { oa0[j] = 0.f; oa1[j] = 0.f; }
  float ls = 0.f;

  // ---- prologue: stage tiles 0 and 1 ----
  gload16(ks0,                  &Ks[0][w * 1024]);
  gload16(ks0 + 512,            &Ks[0][w * 1024 + 512]);
  gload16(vs0,                  &Vs[0][w * 1024]);
  gload16(vs0 + 8 * S_LEN,      &Vs[0][w * 1024 + 512]);
  gload16(ks0 + 4096,           &Ks[1][w * 1024]);
  gload16(ks0 + 4096 + 512,     &Ks[1][w * 1024 + 512]);
  gload16(vs0 + 64,             &Vs[1][w * 1024]);
  gload16(vs0 + 64 + 8 * S_LEN, &Vs[1][w * 1024 + 512]);
  __syncthreads();

  BF8 pf00, pf01, pf10, pf11;      // P frags for the tile awaiting PV

  // ---- QK(0) + exp(0) -> pf ----
  {
    f32x16 s0, s1;
    #pragma unroll
    for (int j = 0; j < 16; ++j) { s0[j] = 0.f; s1[j] = 0.f; }
    qk_cluster((const char*)&Ks[0][0], rb, cx, qf, s0, s1);
    exppack(s0, ls, pf00, pf01);
    exppack(s1, ls, pf10, pf11);
  }
  __syncthreads();   // all waves done reading Ks[0]/QK(0) before body(0) overwrites it

  // rotating buffer pointers
  const char* vA = (const char*)&Vs[0][0];   // PV(t) reads
  const char* vB = (const char*)&Vs[1][0];
  char*       vC = (char*)&Vs[2][0];         // stage target (t+2)
  char*       kS = (char*)&Ks[0][0];         // stage target (t+2)
  const char* kR = (const char*)&Ks[1][0];   // QK(t+1) reads

  for (int t = 0; t < NT - 1; ++t) {
    // ---- stage tile t+2 into freed slots (async, drained at this iter's barrier) ----
    if (t < NT - 2) {
      const unsigned short* kp = ks0 + (size_t)(t + 2) * 4096;
      const unsigned short* vp = vs0 + (t + 2) * 64;
      gload16(kp,             (unsigned short*)kS + w * 1024);
      gload16(kp + 512,       (unsigned short*)kS + w * 1024 + 512);
      gload16(vp,             (unsigned short*)vC + w * 1024);
      gload16(vp + 8 * S_LEN, (unsigned short*)vC + w * 1024 + 512);
    }

    // ---- QK(t+1) ----
    f32x16 s0, s1;
    #pragma unroll
    for (int j = 0; j < 16; ++j) { s0[j] = 0.f; s1[j] = 0.f; }
    qk_cluster(kR, rb, cx, qf, s0, s1);

    // ---- exp/pack(t+1) -> pfn (overlaps PV below via scheduler) ----
    BF8 pn00, pn01, pn10, pn11;
    exppack(s0, ls, pn00, pn01);
    exppack(s1, ls, pn10, pn11);

    // ---- PV(t) with previous pf ----
    pv_cluster(vA, rb, cx, pf00, pf01, pf10, pf11, oa0, oa1);

    pf00 = pn00; pf01 = pn01; pf10 = pn10; pf11 = pn11;

    // rotate buffers
    { const char* tmp = vA; vA = vB; vB = vC; vC = (char*)tmp; }
    { char* tmp = kS; kS = (char*)kR; kR = (const char*)tmp; }

    __syncthreads();   // drains vmcnt (stage t+2 done); guards all buffer flips
  }

  // ---- epilogue: PV(NT-1) ----
  pv_cluster(vA, rb, cx, pf00, pf01, pf10, pf11, oa0, oa1);

  // ---- normalize and store: O[q][d] = O^T[d][q] / l ----
  {
    float lo2 = __shfl_xor(ls, 32);
    float inv = 1.0f / (ls + lo2);
    float* op = O + hbase + (size_t)(q0 + l31) * D_DIM;
    #pragma unroll
    for (int dt = 0; dt < 2; ++dt) {
      const f32x16 oa = dt ? oa1 : oa0;
      #pragma unroll
      for (int b2 = 0; b2 < 4; ++b2) {
        f32x4 vv;
        vv[0] = oa[4 * b2 + 0] * inv;
        vv[1] = oa[4 * b2 + 1] * inv;
        vv[2] = oa[4 * b2 + 2] * inv;
        vv[3] = oa[4 * b2 + 3] * inv;
        *(f32x4*)(op + dt * 32 + b2 * 8 + h * 4) = vv;
      }
    }
  }
}

extern "C" void kernel_launch(void* const* d_in, const int* in_sizes, int n_in,
                              void* d_out, int out_size, void* d_ws, size_t ws_size,
                              hipStream_t stream) {
  const float* q = (const float*)d_in[0];
  const float* k = (const float*)d_in[1];
  const float* v = (const float*)d_in[2];
  float* o = (float*)d_out;
  unsigned short* kb = (unsigned short*)d_ws;
  unsigned short* vt = kb + (size_t)BH_TOTAL * S_LEN * D_DIM;

  cvt_k<<<dim3(4096), 256, 0, stream>>>(k, kb);
  tr_v<<<dim3(2048), 256, 0, stream>>>(v, vt);
  attn_fwd<<<dim3(1024), 256, 0, stream>>>(q, kb, vt, o);
}